// Round 5
// baseline (313.330 us; speedup 1.0000x reference)
//
#include <hip/hip_runtime.h>
#include <math.h>

// ---------------------------------------------------------------------------
// ForceFieldPredictor R17 = R16 with register-pressure surgery:
//   R16: VGPR=236 (compiler CSE'd ntl-invariant weight loads: 16 h8v + 16
//   f4v = 128 VGPR held live across Ph1) -> 2 waves/SIMD, occupancy 9.9%,
//   93.9us, pure latency-bound.
//   R17: (1) Ph1 restructured mt-OUTER: geometry for both ntl first, stage
//   bT[2]/bJ[2] (16 VGPR), single mt loop loads each weight frag ONCE for
//   both ntl MFMAs. (2) __launch_bounds__(64,3): cap ~170 VGPR bounds
//   hoisting depth (live set ~90-130, no spill expected). (3) epilogue
//   scalars (mask/dvx/dvy/hs/hj) stashed to 640B LDS, read in Ph4.
// Transpose (verified R15/R16): b.pair[w] = shfl(p[2ks+(g>>1)][w&1],
//   ((g&1)*2+(w>>1))*16+c), hiSel=g>=2; A[m=l&15][k=(l>>4)*8+j];
//   C col=l&15(query), row=(l>>4)*4+reg (neuron).
// ---------------------------------------------------------------------------

typedef _Float16 h4v __attribute__((ext_vector_type(4)));
typedef _Float16 h8v __attribute__((ext_vector_type(8)));
typedef float    f4v __attribute__((ext_vector_type(4)));
typedef unsigned int u32;

// ---- d_ws layout ----
#define TW0_OFF 0
#define JW0_OFF 4096
#define TWS_OFF 8192
#define BW0_OFF 40960
#define BWS_OFF 45056
#define W_TOTAL 77824      // halfs; brw (fp32) follows
#define BR_OFF_F (W_TOTAL/2)

#define FRAG_BLOCKS 304
#define BR_BLOCKS   256

// ===========================================================================
__global__ __launch_bounds__(256)
void prep_kernel(const float* __restrict__ tw0, const float* __restrict__ tws,
                 const float* __restrict__ jw0, const float* __restrict__ bw0,
                 const float* __restrict__ bws, const float* __restrict__ bb0,
                 const float* __restrict__ bbs, const float* __restrict__ init_x,
                 _Float16* __restrict__ wsH, float* __restrict__ brw)
{
    __shared__ float bsm[2*16*132];       // branch path only (16896 B)
    const int tid = threadIdx.x;

    if (blockIdx.x < FRAG_BLOCKS) {
        int idx = blockIdx.x * 256 + tid;
        if (idx >= W_TOTAL) return;
        const int j = idx & 7;
        const int lane = (idx >> 3) & 63;
        const int q = lane >> 4, r = lane & 15;
        _Float16 v;
        if (idx < JW0_OFF) {                       // trunk w0 (K 9, pad 32)
            int mt = idx >> 9;
            int k = q*8 + j, m = mt*16 + r;
            v = (k < 9) ? (_Float16)tw0[k*128 + m] : (_Float16)0.f;
        } else if (idx < TWS_OFF) {                // joint w0 (K 15, pad 32)
            int mt = (idx - JW0_OFF) >> 9;
            int k = q*8 + j, m = mt*16 + r;
            v = (k < 15) ? (_Float16)jw0[k*128 + m] : (_Float16)0.f;
        } else if (idx < BW0_OFF) {                // trunk ws[0..1]
            int e = idx - TWS_OFF;
            int ks = (e >> 9) & 3, mt = (e >> 11) & 7, l = e >> 14;
            int k = ks*32 + q*8 + j, m = mt*16 + r;
            v = (_Float16)tws[l*16384 + k*128 + m];
        } else if (idx < BWS_OFF) {                // branch w0 (pad)
            int mt = (idx - BW0_OFF) >> 9;
            int k = q*8 + j, m = mt*16 + r;
            v = (k < 5) ? (_Float16)bw0[k*128 + m] : (_Float16)0.f;
        } else {                                   // branch ws[0..1]
            int e = idx - BWS_OFF;
            int ks = (e >> 9) & 3, mt = (e >> 11) & 7, l = e >> 14;
            int k = ks*32 + q*8 + j, m = mt*16 + r;
            v = (_Float16)bws[l*16384 + k*128 + m];
        }
        wsH[idx] = v;
        return;
    }

    // ---- branch MLP: 16 rows per block ------------------------------------
    const int blk2 = blockIdx.x - FRAG_BLOCKS;
    const int row0 = blk2*16;
    const int lane = tid & 63, w = tid >> 6;
    const int q = lane >> 4, r = lane & 15;
    float* h0 = bsm;
    float* h1 = bsm + 16*132;

    for (int e = tid; e < 2048; e += 256) {
        const int rw = e >> 7, n = e & 127;
        const float* ixp = init_x + (row0 + rw)*9;
        float acc = bb0[n];
        acc = fmaf(ixp[2], bw0[2*128 + n], acc);
        acc = fmaf(ixp[3], bw0[3*128 + n], acc);
        acc = fmaf(ixp[4], bw0[4*128 + n], acc);
        h0[rw*132 + n] = acc;
    }
    __syncthreads();

    #pragma unroll
    for (int L = 0; L < 2; ++L) {
        const float* Wg = bws + L*16384;
        const float* bi = bbs + L*128;
        const float* in = (L == 0) ? h0 : h1;
        #pragma unroll
        for (int mi = 0; mi < 2; ++mi) {
            const int mt = w + mi*4;
            const int m0 = mt*16 + q*4;
            h8v af[4];
            #pragma unroll
            for (int ks = 0; ks < 4; ++ks)
                #pragma unroll
                for (int j = 0; j < 8; ++j)
                    af[ks][j] = (_Float16)Wg[(ks*32 + q*8 + j)*128 + mt*16 + r];
            f4v acc = *(const f4v*)&bi[m0];
            #pragma unroll
            for (int ks = 0; ks < 4; ++ks) {
                f4v x0 = *(const f4v*)&in[r*132 + ks*32 + q*8];
                f4v x1 = *(const f4v*)&in[r*132 + ks*32 + q*8 + 4];
                h8v bf;
                #pragma unroll
                for (int i = 0; i < 4; ++i) {
                    bf[i]   = (_Float16)fmaxf(x0[i], 0.f);
                    bf[4+i] = (_Float16)fmaxf(x1[i], 0.f);
                }
                acc = __builtin_amdgcn_mfma_f32_16x16x32_f16(af[ks], bf, acc, 0, 0, 0);
            }
            if (L == 0)
                *(f4v*)&h1[r*132 + m0] = acc;
            else
                *(f4v*)&brw[(row0 + r)*128 + m0] = acc;
        }
        __syncthreads();
    }
}

// ===========================================================================
__device__ __forceinline__ u32 sh_u32(u32 v, int idx) {
    return (u32)__shfl((int)v, idx, 64);
}
__device__ __forceinline__ h8v make_h8(u32 a, u32 b, u32 c, u32 d) {
    union { u32 u[4]; h8v h; } t;
    t.u[0] = a; t.u[1] = b; t.u[2] = c; t.u[3] = d;
    return t.h;
}
__device__ __forceinline__ u32 pack_relu2(float x, float y) {
    union { _Float16 h[2]; u32 u; } t;
    t.h[0] = (_Float16)fmaxf(x, 0.f);
    t.h[1] = (_Float16)fmaxf(y, 0.f);
    return t.u;
}

// Build B-frag (K=32 sub-tile ks) for next layer from packed acts p[8][2].
// Elements j=2w,2w+1 of lane (g*16+c) = acts[ks*32 + g*8 + 2w .. +1][c].
#define BUILD_BF(dst, P) do {                                                 \
    _Pragma("unroll")                                                         \
    for (int ks_ = 0; ks_ < 4; ++ks_) {                                       \
        u32 lo0 = sh_u32((P)[2*ks_][0],   idxA);                              \
        u32 hi0 = sh_u32((P)[2*ks_+1][0], idxA);                              \
        u32 lo1 = sh_u32((P)[2*ks_][1],   idxA);                              \
        u32 hi1 = sh_u32((P)[2*ks_+1][1], idxA);                              \
        u32 lo2 = sh_u32((P)[2*ks_][0],   idxB);                              \
        u32 hi2 = sh_u32((P)[2*ks_+1][0], idxB);                              \
        u32 lo3 = sh_u32((P)[2*ks_][1],   idxB);                              \
        u32 hi3 = sh_u32((P)[2*ks_+1][1], idxB);                              \
        (dst)[ks_] = make_h8(hiSel ? hi0 : lo0, hiSel ? hi1 : lo1,            \
                             hiSel ? hi2 : lo2, hiSel ? hi3 : lo3);           \
    }                                                                         \
} while (0)

// ===========================================================================
__global__ __launch_bounds__(64, 3)
void ff_kernel(const float* __restrict__ init_x,  const float* __restrict__ query_x,
               const float* __restrict__ init_v,  const float* __restrict__ query_v,
               const float* __restrict__ init_av, const float* __restrict__ query_av,
               const float* __restrict__ tb0, const float* __restrict__ tbs,
               const float* __restrict__ out_w, const float* __restrict__ out_b,
               const float* __restrict__ sw0, const float* __restrict__ sb0,
               const float* __restrict__ sw1, const float* __restrict__ sb1,
               const float* __restrict__ jb0,
               const float* __restrict__ jw1, const float* __restrict__ jb1,
               const _Float16* __restrict__ wsH, const float* __restrict__ brw,
               float* __restrict__ out)
{
    __shared__ float es[5*32];             // epilogue stash [5][ntl*16+c]
    const int lane = threadIdx.x;          // 0..63
    const int bid  = blockIdx.x;           // (b*64+o)*2 + half
    const int obid = bid >> 1;             // b*64 + o
    const int half = bid & 1;
    const int b    = obid >> 6;
    const int g    = lane >> 4, c = lane & 15;
    const int idxA = (g & 1)*32 + c;       // src lane for B-pairs w=0,1
    const int idxB = idxA + 16;            // src lane for B-pairs w=2,3
    const bool hiSel = (lane & 32) != 0;   // g>=2 reads p[2ks+1]

    // ---- uniform init-capsule quantities (live only through Ph1) -----------
    const float* ix = init_x + obid*9;
    const float ix0 = ix[0], ix1 = ix[1], ix2 = ix[2], ix3 = ix[3], ix4 = ix[4];
    const float ix7 = ix[7], ix8 = ix[8];
    float s1v, c1v; sincosf(ix3 * 100.f, &s1v, &c1v);
    const float hh1 = ix2 * 0.5f;
    const float o1x = hh1*c1v, o1y = hh1*s1v;
    const float A1x = -o1x, A1y = -o1y;
    const float ab1x = 2.f*o1x, ab1y = 2.f*o1y;
    const float s1sq = ab1x*ab1x + ab1y*ab1y + 1e-8f;
    const float iv0 = init_v[obid*2+0], iv1 = init_v[obid*2+1];
    const float iav = init_av[obid];
    const float i7t = truncf(ix7);
    const float fr7 = ix7 - i7t;

    u32  p[2][8][2];                       // packed fp16 acts [ntl][mt][h]
    float len_[2];
    h8v bT[2], bJ[2];

    // ---- Ph1a: geometry for BOTH n-tiles -> staged B-frags + LDS stash -----
    #pragma unroll
    for (int ntl = 0; ntl < 2; ++ntl) {
        const int tq = (half*2 + ntl)*16 + c;
        const float* qx = query_x + (b*64 + tq)*9;
        const float qx0 = qx[0], qx1 = qx[1], qx2 = qx[2], qx3 = qx[3], qx4 = qx[4];
        const float qx7 = qx[7], qx8 = qx[8];
        const float rel0 = qx0 - ix0, rel1 = qx1 - ix1;

        float s2v, c2v; sincosf(qx3 * 100.f, &s2v, &c2v);
        const float hh2 = qx2 * 0.5f;
        const float o2x = hh2*c2v, o2y = hh2*s2v;
        const float A2x = rel0 - o2x, A2y = rel1 - o2y;
        const float B2x = rel0 + o2x, B2y = rel1 + o2y;
        const float ab2x = 2.f*o2x, ab2y = 2.f*o2y;
        const float s2sq = ab2x*ab2x + ab2y*ab2y + 1e-8f;

        float Px, Py, Ax, Ay, ABx, ABy, ss;
        if (g < 2) {
            Ax = A1x; Ay = A1y; ABx = ab1x; ABy = ab1y; ss = s1sq;
            Px = (g == 0) ? A2x : B2x;  Py = (g == 0) ? A2y : B2y;
        } else {
            Ax = A2x; Ay = A2y; ABx = ab2x; ABy = ab2y; ss = s2sq;
            Px = (g == 2) ? A1x : o1x;  Py = (g == 2) ? A1y : o1y;
        }
        float t = ((Px - Ax)*ABx + (Py - Ay)*ABy) / ss;
        t = fminf(fmaxf(t, 0.f), 1.f);
        const float dx = Px - (Ax + t*ABx);
        const float dy = Py - (Ay + t*ABy);
        float dq = sqrtf(dx*dx + dy*dy);
        dq = fminf(dq, __shfl_xor(dq, 16));     // min over cand bit0
        dq = fminf(dq, __shfl_xor(dq, 32));     // min over cand bit1

        const float dist = dq - ix4 - qx4;
        const float mask = (dist <= 0.f) ? 1.f : 0.f;
        const float dinp = dist * mask * 100.f;
        const float qv0 = query_v[(b*64+tq)*2+0] - iv0;
        const float qv1 = query_v[(b*64+tq)*2+1] - iv1;
        const float qav = query_av[b*64+tq] - iav;
        const float len = sqrtf(rel0*rel0 + rel1*rel1);
        const float inv = 1.f / (len + 1e-8f);
        len_[ntl] = len;

        if (g == 0) {                      // stash epilogue scalars (640B LDS)
            es[0*32 + ntl*16 + c] = mask;
            es[1*32 + ntl*16 + c] = -rel0 * inv;
            es[2*32 + ntl*16 + c] = -rel1 * inv;
            es[3*32 + ntl*16 + c] = ((ix8 == qx8) && (ix8 > 0.f)) ? 1.f : 0.f;
            es[4*32 + ntl*16 + c] = ((i7t == truncf(qx7)) && (ix7 > 0.f)) ? 1.f : 0.f;
        }

        // B-frags straight from registers: element j = feature g*8+j
        const bool g0 = (g == 0), g1 = (g == 1);
        bT[ntl][0] = (_Float16)(g0 ? rel0 : g1 ? dinp : 0.f);
        bT[ntl][1] = (_Float16)(g0 ? rel1 : 0.f);
        bT[ntl][2] = (_Float16)(g0 ? qx2  : 0.f);
        bT[ntl][3] = (_Float16)(g0 ? qx3  : 0.f);
        bT[ntl][4] = (_Float16)(g0 ? qx4  : 0.f);
        bT[ntl][5] = (_Float16)(g0 ? qv0  : 0.f);
        bT[ntl][6] = (_Float16)(g0 ? qv1  : 0.f);
        bT[ntl][7] = (_Float16)(g0 ? qav  : 0.f);
        bJ[ntl][0] = (_Float16)(g1 ? qx3  : 0.f);
        bJ[ntl][1] = (_Float16)(g1 ? qx4  : 0.f);
        bJ[ntl][2] = (_Float16)(g0 ? ix2  : g1 ? qv0 : 0.f);
        bJ[ntl][3] = (_Float16)(g0 ? ix3  : g1 ? qv1 : 0.f);
        bJ[ntl][4] = (_Float16)(g0 ? ix4  : g1 ? iav : 0.f);
        bJ[ntl][5] = (_Float16)(g0 ? rel0 : g1 ? qav : 0.f);
        bJ[ntl][6] = (_Float16)(g0 ? rel1 : g1 ? fr7 : 0.f);
        bJ[ntl][7] = (_Float16)(g0 ? qx2  : 0.f);
    }

    // ---- Ph1b: L0 trunk + joint, each weight frag loaded ONCE --------------
    float jf0_[2] = {0.f, 0.f}, jf1_[2] = {0.f, 0.f};
    #pragma unroll
    for (int mt = 0; mt < 8; ++mt) {
        const int m0 = mt*16 + g*4;
        h8v aT = *(const h8v*)&wsH[TW0_OFF + (mt*64 + lane)*8];
        f4v tb = *(const f4v*)&tb0[m0];
        f4v acc0 = __builtin_amdgcn_mfma_f32_16x16x32_f16(aT, bT[0], tb, 0, 0, 0);
        f4v acc1 = __builtin_amdgcn_mfma_f32_16x16x32_f16(aT, bT[1], tb, 0, 0, 0);
        p[0][mt][0] = pack_relu2(acc0[0], acc0[1]);
        p[0][mt][1] = pack_relu2(acc0[2], acc0[3]);
        p[1][mt][0] = pack_relu2(acc1[0], acc1[1]);
        p[1][mt][1] = pack_relu2(acc1[2], acc1[3]);

        h8v aJ = *(const h8v*)&wsH[JW0_OFF + (mt*64 + lane)*8];
        f4v jb = *(const f4v*)&jb0[m0];
        f4v aj0 = __builtin_amdgcn_mfma_f32_16x16x32_f16(aJ, bJ[0], jb, 0, 0, 0);
        f4v aj1 = __builtin_amdgcn_mfma_f32_16x16x32_f16(aJ, bJ[1], jb, 0, 0, 0);
        f4v jwa = *(const f4v*)&jw1[m0*2];
        f4v jwb = *(const f4v*)&jw1[m0*2 + 4];
        {
            const float h0r = fmaxf(aj0[0], 0.f), h1r = fmaxf(aj0[1], 0.f);
            const float h2r = fmaxf(aj0[2], 0.f), h3r = fmaxf(aj0[3], 0.f);
            jf0_[0] = fmaf(h0r, jwa[0], fmaf(h1r, jwa[2], fmaf(h2r, jwb[0], fmaf(h3r, jwb[2], jf0_[0]))));
            jf1_[0] = fmaf(h0r, jwa[1], fmaf(h1r, jwa[3], fmaf(h2r, jwb[1], fmaf(h3r, jwb[3], jf1_[0]))));
        }
        {
            const float h0r = fmaxf(aj1[0], 0.f), h1r = fmaxf(aj1[1], 0.f);
            const float h2r = fmaxf(aj1[2], 0.f), h3r = fmaxf(aj1[3], 0.f);
            jf0_[1] = fmaf(h0r, jwa[0], fmaf(h1r, jwa[2], fmaf(h2r, jwb[0], fmaf(h3r, jwb[2], jf0_[1]))));
            jf1_[1] = fmaf(h0r, jwa[1], fmaf(h1r, jwa[3], fmaf(h2r, jwb[1], fmaf(h3r, jwb[3], jf1_[1]))));
        }
    }

    // ---- spring MLP (1->128->1), neurons g*32..g*32+31 per lane ------------
    float sp_[2] = {0.f, 0.f};
    #pragma unroll
    for (int ch = 0; ch < 8; ++ch) {
        const int n0 = g*32 + ch*4;
        f4v w0v = *(const f4v*)&sw0[n0];
        f4v b0v = *(const f4v*)&sb0[n0];
        f4v w1v = *(const f4v*)&sw1[n0];
        #pragma unroll
        for (int i = 0; i < 4; ++i)
            #pragma unroll
            for (int ntl = 0; ntl < 2; ++ntl)
                sp_[ntl] = fmaf(fmaxf(fmaf(len_[ntl], w0v[i], b0v[i]), 0.f), w1v[i], sp_[ntl]);
    }

    // ---- Ph2: trunk L1 (in-register transpose via shfl) --------------------
    {
        h8v bf[2][4];
        #pragma unroll
        for (int n2 = 0; n2 < 2; ++n2)
            BUILD_BF(bf[n2], p[n2]);
        #pragma unroll
        for (int mt = 0; mt < 8; ++mt) {
            h8v a0 = *(const h8v*)&wsH[TWS_OFF + ((mt*4 + 0)*64 + lane)*8];
            h8v a1 = *(const h8v*)&wsH[TWS_OFF + ((mt*4 + 1)*64 + lane)*8];
            h8v a2 = *(const h8v*)&wsH[TWS_OFF + ((mt*4 + 2)*64 + lane)*8];
            h8v a3 = *(const h8v*)&wsH[TWS_OFF + ((mt*4 + 3)*64 + lane)*8];
            f4v bias = *(const f4v*)&tbs[mt*16 + g*4];
            #pragma unroll
            for (int n2 = 0; n2 < 2; ++n2) {
                f4v acc = bias;
                acc = __builtin_amdgcn_mfma_f32_16x16x32_f16(a0, bf[n2][0], acc, 0, 0, 0);
                acc = __builtin_amdgcn_mfma_f32_16x16x32_f16(a1, bf[n2][1], acc, 0, 0, 0);
                acc = __builtin_amdgcn_mfma_f32_16x16x32_f16(a2, bf[n2][2], acc, 0, 0, 0);
                acc = __builtin_amdgcn_mfma_f32_16x16x32_f16(a3, bf[n2][3], acc, 0, 0, 0);
                p[n2][mt][0] = pack_relu2(acc[0], acc[1]);
                p[n2][mt][1] = pack_relu2(acc[2], acc[3]);
            }
        }
    }

    // ---- Ph3: trunk L2 + branch*trunk@out_w fold ---------------------------
    float f0_[2] = {0,0}, f1_[2] = {0,0}, f2_[2] = {0,0};
    {
        h8v bf[2][4];
        #pragma unroll
        for (int n2 = 0; n2 < 2; ++n2)
            BUILD_BF(bf[n2], p[n2]);
        #pragma unroll
        for (int mt = 0; mt < 8; ++mt) {
            const int m0 = mt*16 + g*4;
            h8v a0 = *(const h8v*)&wsH[TWS_OFF + 16384 + ((mt*4 + 0)*64 + lane)*8];
            h8v a1 = *(const h8v*)&wsH[TWS_OFF + 16384 + ((mt*4 + 1)*64 + lane)*8];
            h8v a2 = *(const h8v*)&wsH[TWS_OFF + 16384 + ((mt*4 + 2)*64 + lane)*8];
            h8v a3 = *(const h8v*)&wsH[TWS_OFF + 16384 + ((mt*4 + 3)*64 + lane)*8];
            f4v bias = *(const f4v*)&tbs[128 + m0];
            f4v brv  = *(const f4v*)&brw[obid*128 + m0];
            f4v oa = *(const f4v*)&out_w[m0*3];
            f4v ob = *(const f4v*)&out_w[m0*3 + 4];
            f4v oc = *(const f4v*)&out_w[m0*3 + 8];
            #pragma unroll
            for (int n2 = 0; n2 < 2; ++n2) {
                f4v acc = bias;
                acc = __builtin_amdgcn_mfma_f32_16x16x32_f16(a0, bf[n2][0], acc, 0, 0, 0);
                acc = __builtin_amdgcn_mfma_f32_16x16x32_f16(a1, bf[n2][1], acc, 0, 0, 0);
                acc = __builtin_amdgcn_mfma_f32_16x16x32_f16(a2, bf[n2][2], acc, 0, 0, 0);
                acc = __builtin_amdgcn_mfma_f32_16x16x32_f16(a3, bf[n2][3], acc, 0, 0, 0);
                const float pr0 = acc[0]*brv[0], pr1 = acc[1]*brv[1];
                const float pr2 = acc[2]*brv[2], pr3 = acc[3]*brv[3];
                f0_[n2] += pr0*oa[0] + pr1*oa[3] + pr2*ob[2] + pr3*oc[1];
                f1_[n2] += pr0*oa[1] + pr1*ob[0] + pr2*ob[3] + pr3*oc[2];
                f2_[n2] += pr0*oa[2] + pr1*ob[1] + pr2*oc[0] + pr3*oc[3];
            }
        }
    }

    // ---- Ph4: reduce over lane-groups + store ------------------------------
    const float obs0 = out_b[0], obs1 = out_b[1], obs2 = out_b[2];
    const float sb1v = sb1[0], jb1a = jb1[0], jb1b = jb1[1];
    #pragma unroll
    for (int ntl = 0; ntl < 2; ++ntl) {
        float v0 = f0_[ntl], v1 = f1_[ntl], v2 = f2_[ntl];
        float v3 = jf0_[ntl], v4 = jf1_[ntl], v5 = sp_[ntl];
        v0 += __shfl_xor(v0, 16); v0 += __shfl_xor(v0, 32);
        v1 += __shfl_xor(v1, 16); v1 += __shfl_xor(v1, 32);
        v2 += __shfl_xor(v2, 16); v2 += __shfl_xor(v2, 32);
        v3 += __shfl_xor(v3, 16); v3 += __shfl_xor(v3, 32);
        v4 += __shfl_xor(v4, 16); v4 += __shfl_xor(v4, 32);
        v5 += __shfl_xor(v5, 16); v5 += __shfl_xor(v5, 32);
        if (g == 0) {
            const float mask = es[0*32 + ntl*16 + c];
            const float dvx  = es[1*32 + ntl*16 + c];
            const float dvy  = es[2*32 + ntl*16 + c];
            const float hs   = es[3*32 + ntl*16 + c];
            const float hj   = es[4*32 + ntl*16 + c];
            const float sf = (v5 + sb1v) * hs;
            const float j0 = (v3 + jb1a) * hj;
            const float j1 = (v4 + jb1b) * hj;
            float* op = out + (obid*64 + (half*2 + ntl)*16 + c)*3;
            op[0] = (v0 + obs0)*mask + sf*dvx + j0;
            op[1] = (v1 + obs1)*mask + sf*dvy + j1;
            op[2] = (v2 + obs2)*mask;
        }
    }
}

// ===========================================================================
extern "C" void kernel_launch(void* const* d_in, const int* in_sizes, int n_in,
                              void* d_out, int out_size, void* d_ws, size_t ws_size,
                              hipStream_t stream) {
    (void)in_sizes; (void)n_in; (void)out_size; (void)ws_size;
    _Float16* wsH = (_Float16*)d_ws;
    float* brw = (float*)d_ws + BR_OFF_F;

    prep_kernel<<<dim3(FRAG_BLOCKS + BR_BLOCKS), dim3(256), 0, stream>>>(
        (const float*)d_in[6],   // trunk_w0
        (const float*)d_in[8],   // trunk_ws
        (const float*)d_in[20],  // joint_w0
        (const float*)d_in[10],  // branch_w0
        (const float*)d_in[12],  // branch_ws
        (const float*)d_in[11],  // branch_b0
        (const float*)d_in[13],  // branch_bs
        (const float*)d_in[0],   // init_x
        wsH, brw);
    ff_kernel<<<dim3(64*64*2), dim3(64), 0, stream>>>(
        (const float*)d_in[0],  (const float*)d_in[1],  (const float*)d_in[2],
        (const float*)d_in[3],  (const float*)d_in[4],  (const float*)d_in[5],
        (const float*)d_in[7],  (const float*)d_in[9],                  // tb0, tbs
        (const float*)d_in[14], (const float*)d_in[15],                 // out_w, out_b
        (const float*)d_in[16], (const float*)d_in[17],                 // sw0, sb0
        (const float*)d_in[18], (const float*)d_in[19],                 // sw1, sb1
        (const float*)d_in[21],                                         // jb0
        (const float*)d_in[22], (const float*)d_in[23],                 // jw1, jb1
        wsH, brw, (float*)d_out);
}

// Round 6
// 155.604 us; speedup vs baseline: 2.0136x; 2.0136x over previous
//
#include <hip/hip_runtime.h>
#include <math.h>

// ---------------------------------------------------------------------------
// ForceFieldPredictor R18 = R12 (best verified: ff=60us, total 155.4us)
// + ONE change: fred stride 24 -> 7 dwords.
//   R12 P5 reads at stride 24: bank = 24t mod 32 in {0,8,16,24} -> 16
//   lanes/bank (~5.7x serialization); P4 writes 4-way. gcd(7,32)=1 ->
//   both <=2 lanes/bank (free, m136). fred needs 64*4*7=1792 floats
//   (7168 B) < ACTA region (17408 B). Everything else byte-identical R12.
//   (R13-R17 wave-autonomous exploration: structure verified correct but
//   needs ~200 VGPR no-spill at only 2 waves/SIMD -> latency scissors;
//   spill storms at any clamp. Branch abandoned per R16 decision rule.)
// F_RED overlays ACTA (dead after P3) -> LDS 36352 B -> 4 blocks/CU at
// VGPR=84 (LDS-limited), no allocator pressure.
// Layouts (verified R3-R11): A[m=l&15][k=(l>>4)*8+j], B[k][n=l&15],
// C col=l&15, row=(l>>4)*4+reg.
// ---------------------------------------------------------------------------

typedef _Float16 h4v __attribute__((ext_vector_type(4)));
typedef _Float16 h8v __attribute__((ext_vector_type(8)));
typedef float    f4v __attribute__((ext_vector_type(4)));

#define AH 136

// ---- d_ws layout ----
#define TW0_OFF 0
#define JW0_OFF 4096
#define TWS_OFF 8192
#define BW0_OFF 40960
#define BWS_OFF 45056
#define W_TOTAL 77824      // halfs; brw (fp32) follows
#define BR_OFF_F (W_TOTAL/2)

// ---- ff LDS halfs (TINB/JINB overlay ACTB; F_RED overlays ACTA in P4+) ----
#define H_ACTA 0
#define H_ACTB 8704
#define H_TINB 8704
#define H_JINB 10752
#define SMH_SIZE 17408          // 34816 B

// ---- ff LDS floats (scalars only) ----
#define F_SCAL  0
#define SMF_SIZE 384            // 1536 B (total 36352 B -> 4 blk/CU)

#define FRAG_BLOCKS 304
#define BR_BLOCKS   256

// ===========================================================================
__global__ __launch_bounds__(256)
void prep_kernel(const float* __restrict__ tw0, const float* __restrict__ tws,
                 const float* __restrict__ jw0, const float* __restrict__ bw0,
                 const float* __restrict__ bws, const float* __restrict__ bb0,
                 const float* __restrict__ bbs, const float* __restrict__ init_x,
                 _Float16* __restrict__ wsH, float* __restrict__ brw)
{
    __shared__ float bsm[2*16*132];       // branch path only (16896 B)
    const int tid = threadIdx.x;

    if (blockIdx.x < FRAG_BLOCKS) {
        int idx = blockIdx.x * 256 + tid;
        if (idx >= W_TOTAL) return;
        const int j = idx & 7;
        const int lane = (idx >> 3) & 63;
        const int q = lane >> 4, r = lane & 15;
        _Float16 v;
        if (idx < JW0_OFF) {                       // trunk w0 (K 9, pad 32)
            int mt = idx >> 9;
            int k = q*8 + j, m = mt*16 + r;
            v = (k < 9) ? (_Float16)tw0[k*128 + m] : (_Float16)0.f;
        } else if (idx < TWS_OFF) {                // joint w0 (K 15, pad 32)
            int mt = (idx - JW0_OFF) >> 9;
            int k = q*8 + j, m = mt*16 + r;
            v = (k < 15) ? (_Float16)jw0[k*128 + m] : (_Float16)0.f;
        } else if (idx < BW0_OFF) {                // trunk ws[0..1]
            int e = idx - TWS_OFF;
            int ks = (e >> 9) & 3, mt = (e >> 11) & 7, l = e >> 14;
            int k = ks*32 + q*8 + j, m = mt*16 + r;
            v = (_Float16)tws[l*16384 + k*128 + m];
        } else if (idx < BWS_OFF) {                // branch w0 (pad)
            int mt = (idx - BW0_OFF) >> 9;
            int k = q*8 + j, m = mt*16 + r;
            v = (k < 5) ? (_Float16)bw0[k*128 + m] : (_Float16)0.f;
        } else {                                   // branch ws[0..1]
            int e = idx - BWS_OFF;
            int ks = (e >> 9) & 3, mt = (e >> 11) & 7, l = e >> 14;
            int k = ks*32 + q*8 + j, m = mt*16 + r;
            v = (_Float16)bws[l*16384 + k*128 + m];
        }
        wsH[idx] = v;
        return;
    }

    // ---- branch MLP: 16 rows per block ------------------------------------
    const int blk2 = blockIdx.x - FRAG_BLOCKS;
    const int row0 = blk2*16;
    const int lane = tid & 63, w = tid >> 6;
    const int q = lane >> 4, r = lane & 15;
    float* h0 = bsm;
    float* h1 = bsm + 16*132;

    for (int e = tid; e < 2048; e += 256) {
        const int rw = e >> 7, n = e & 127;
        const float* ixp = init_x + (row0 + rw)*9;
        float acc = bb0[n];
        acc = fmaf(ixp[2], bw0[2*128 + n], acc);
        acc = fmaf(ixp[3], bw0[3*128 + n], acc);
        acc = fmaf(ixp[4], bw0[4*128 + n], acc);
        h0[rw*132 + n] = acc;
    }
    __syncthreads();

    #pragma unroll
    for (int L = 0; L < 2; ++L) {
        const float* Wg = bws + L*16384;
        const float* bi = bbs + L*128;
        const float* in = (L == 0) ? h0 : h1;
        #pragma unroll
        for (int mi = 0; mi < 2; ++mi) {
            const int mt = w + mi*4;
            const int m0 = mt*16 + q*4;
            h8v af[4];
            #pragma unroll
            for (int ks = 0; ks < 4; ++ks)
                #pragma unroll
                for (int j = 0; j < 8; ++j)
                    af[ks][j] = (_Float16)Wg[(ks*32 + q*8 + j)*128 + mt*16 + r];
            f4v acc = *(const f4v*)&bi[m0];
            #pragma unroll
            for (int ks = 0; ks < 4; ++ks) {
                f4v x0 = *(const f4v*)&in[r*132 + ks*32 + q*8];
                f4v x1 = *(const f4v*)&in[r*132 + ks*32 + q*8 + 4];
                h8v bf;
                #pragma unroll
                for (int i = 0; i < 4; ++i) {
                    bf[i]   = (_Float16)fmaxf(x0[i], 0.f);
                    bf[4+i] = (_Float16)fmaxf(x1[i], 0.f);
                }
                acc = __builtin_amdgcn_mfma_f32_16x16x32_f16(af[ks], bf, acc, 0, 0, 0);
            }
            if (L == 0)
                *(f4v*)&h1[r*132 + m0] = acc;
            else
                *(f4v*)&brw[(row0 + r)*128 + m0] = acc;
        }
        __syncthreads();
    }
}

// ===========================================================================
__device__ __forceinline__ void layerK32_rw(const h8v af[2],
        const float* __restrict__ bias, const _Float16* __restrict__ inB,
        _Float16* __restrict__ actOut, int lane, int w)
{
    const int q = lane >> 4, r = lane & 15;
    #pragma unroll
    for (int nt = 0; nt < 4; ++nt) {
        h8v bf = *(const h8v*)&inB[(nt*64 + lane)*8];
        #pragma unroll
        for (int mi = 0; mi < 2; ++mi) {
            f4v acc = *(const f4v*)&bias[(2*w + mi)*16 + q*4];
            acc = __builtin_amdgcn_mfma_f32_16x16x32_f16(af[mi], bf, acc, 0, 0, 0);
            h4v o;
            #pragma unroll
            for (int i = 0; i < 4; ++i) o[i] = (_Float16)fmaxf(acc[i], 0.f);
            *(h4v*)&actOut[(nt*16 + r)*AH + (2*w + mi)*16 + q*4] = o;
        }
    }
}

__device__ __forceinline__ void layerK128_rw(const h8v af[2][4],
        const float* __restrict__ bias, const _Float16* __restrict__ actIn,
        _Float16* __restrict__ actOut, int lane, int w)
{
    const int q = lane >> 4, r = lane & 15;
    #pragma unroll
    for (int nt = 0; nt < 4; ++nt) {
        h8v bf[4];
        #pragma unroll
        for (int ks = 0; ks < 4; ++ks)
            bf[ks] = *(const h8v*)&actIn[(nt*16 + r)*AH + ks*32 + q*8];
        #pragma unroll
        for (int mi = 0; mi < 2; ++mi) {
            f4v acc = *(const f4v*)&bias[(2*w + mi)*16 + q*4];
            #pragma unroll
            for (int ks = 0; ks < 4; ++ks)
                acc = __builtin_amdgcn_mfma_f32_16x16x32_f16(af[mi][ks], bf[ks], acc, 0, 0, 0);
            h4v o;
            #pragma unroll
            for (int i = 0; i < 4; ++i) o[i] = (_Float16)fmaxf(acc[i], 0.f);
            *(h4v*)&actOut[(nt*16 + r)*AH + (2*w + mi)*16 + q*4] = o;
        }
    }
}

__device__ __forceinline__ void layerK128_regs_rw(const h8v af[2][4],
        const float* __restrict__ bias, const _Float16* __restrict__ actIn,
        f4v accT[2][4], int lane, int w)
{
    const int q = lane >> 4, r = lane & 15;
    #pragma unroll
    for (int nt = 0; nt < 4; ++nt) {
        h8v bf[4];
        #pragma unroll
        for (int ks = 0; ks < 4; ++ks)
            bf[ks] = *(const h8v*)&actIn[(nt*16 + r)*AH + ks*32 + q*8];
        #pragma unroll
        for (int mi = 0; mi < 2; ++mi) {
            f4v acc = *(const f4v*)&bias[(2*w + mi)*16 + q*4];
            #pragma unroll
            for (int ks = 0; ks < 4; ++ks)
                acc = __builtin_amdgcn_mfma_f32_16x16x32_f16(af[mi][ks], bf[ks], acc, 0, 0, 0);
            accT[mi][nt] = acc;
        }
    }
}

// ===========================================================================
__global__ __launch_bounds__(256, 3)
void ff_kernel(const float* __restrict__ init_x,  const float* __restrict__ query_x,
               const float* __restrict__ init_v,  const float* __restrict__ query_v,
               const float* __restrict__ init_av, const float* __restrict__ query_av,
               const float* __restrict__ tb0, const float* __restrict__ tbs,
               const float* __restrict__ out_w, const float* __restrict__ out_b,
               const float* __restrict__ sw0, const float* __restrict__ sb0,
               const float* __restrict__ sw1, const float* __restrict__ sb1,
               const float* __restrict__ jb0,
               const float* __restrict__ jw1, const float* __restrict__ jb1,
               const _Float16* __restrict__ wsH, const float* __restrict__ brw,
               float* __restrict__ out)
{
    __shared__ __align__(16) _Float16 smh[SMH_SIZE];
    __shared__ float smf[SMF_SIZE];
    float* const fred = (float*)smh;            // overlays ACTA (dead in P4+)
    const int tid = threadIdx.x;
    const int bid = blockIdx.x;
    const int o  = bid & 63;
    const int b  = bid >> 6;
    const int lane = tid & 63, w = tid >> 6;
    const int q = lane >> 4, r = lane & 15;
    const float* ix = init_x + (b*64 + o)*9;

    // ---- P0: prefetch all weight A-frags + branch_out into registers ------
    h8v afT0[2], afJ0[2], afT1[2][4], afT2[2][4];
    f4v br[2];
    #pragma unroll
    for (int mi = 0; mi < 2; ++mi) {
        const int mtg = 2*w + mi;
        afT0[mi] = *(const h8v*)&wsH[TW0_OFF + (mtg*64 + lane)*8];
        afJ0[mi] = *(const h8v*)&wsH[JW0_OFF + (mtg*64 + lane)*8];
        #pragma unroll
        for (int ks = 0; ks < 4; ++ks) {
            afT1[mi][ks] = *(const h8v*)&wsH[TWS_OFF + ((mtg*4 + ks)*64 + lane)*8];
            afT2[mi][ks] = *(const h8v*)&wsH[TWS_OFF + 16384 + ((mtg*4 + ks)*64 + lane)*8];
        }
        br[mi] = *(const f4v*)&brw[bid*128 + mtg*16 + q*4];
    }

    // ---- P1: geometry (all 4 waves; row = w*16+r, quad q -> one pseg) ------
    {
        const int tq = w*16 + r;
        const float* qx = query_x + (b*64 + tq)*9;
        const float ix0 = ix[0], ix1 = ix[1], ix2 = ix[2], ix3 = ix[3], ix4 = ix[4];
        const float ix7 = ix[7], ix8 = ix[8];
        const float qx0 = qx[0], qx1 = qx[1], qx2 = qx[2], qx3 = qx[3], qx4 = qx[4];
        const float qx7 = qx[7], qx8 = qx[8];
        const float rel0 = qx0 - ix0, rel1 = qx1 - ix1;

        float s1v, c1v; sincosf(ix3 * 100.f, &s1v, &c1v);
        float s2v, c2v; sincosf(qx3 * 100.f, &s2v, &c2v);
        const float h1 = ix2 * 0.5f, h2 = qx2 * 0.5f;
        const float o1x = h1*c1v, o1y = h1*s1v;
        const float o2x = h2*c2v, o2y = h2*s2v;
        const float A1x = -o1x, A1y = -o1y;
        const float A2x = rel0 - o2x, A2y = rel1 - o2y;
        const float B2x = rel0 + o2x, B2y = rel1 + o2y;
        const float ab1x = 2.f*o1x, ab1y = 2.f*o1y;
        const float ab2x = 2.f*o2x, ab2y = 2.f*o2y;
        const float s1sq = ab1x*ab1x + ab1y*ab1y + 1e-8f;
        const float s2sq = ab2x*ab2x + ab2y*ab2y + 1e-8f;

        float Px, Py, Ax, Ay, ABx, ABy, ss;
        if (q < 2) {
            Ax = A1x; Ay = A1y; ABx = ab1x; ABy = ab1y; ss = s1sq;
            Px = (q == 0) ? A2x : B2x;  Py = (q == 0) ? A2y : B2y;
        } else {
            Ax = A2x; Ay = A2y; ABx = ab2x; ABy = ab2y; ss = s2sq;
            Px = (q == 2) ? A1x : o1x;  Py = (q == 2) ? A1y : o1y;
        }
        float t = ((Px - Ax)*ABx + (Py - Ay)*ABy) / ss;
        t = fminf(fmaxf(t, 0.f), 1.f);
        const float dx = Px - (Ax + t*ABx);
        const float dy = Py - (Ay + t*ABy);
        float dq = sqrtf(dx*dx + dy*dy);
        dq = fminf(dq, __shfl_xor(dq, 16));
        dq = fminf(dq, __shfl_xor(dq, 32));

        if (q == 0) {
            const float dist = dq - ix4 - qx4;
            const float mask = (dist <= 0.f) ? 1.f : 0.f;
            const float dinp = dist * mask * 100.f;
            const float qv0 = query_v[(b*64+tq)*2+0] - init_v[(b*64+o)*2+0];
            const float qv1 = query_v[(b*64+tq)*2+1] - init_v[(b*64+o)*2+1];
            const float iav = init_av[b*64+o];
            const float qav = query_av[b*64+tq] - iav;

            const int fb = w*512 + r*8;
            h8v t0, t1 = {}, z = {};
            t0[0]=(_Float16)rel0; t0[1]=(_Float16)rel1; t0[2]=(_Float16)qx2;
            t0[3]=(_Float16)qx3;  t0[4]=(_Float16)qx4;  t0[5]=(_Float16)qv0;
            t0[6]=(_Float16)qv1;  t0[7]=(_Float16)qav;
            t1[0]=(_Float16)dinp;
            *(h8v*)&smh[H_TINB + fb]       = t0;
            *(h8v*)&smh[H_TINB + fb + 128] = t1;
            *(h8v*)&smh[H_TINB + fb + 256] = z;
            *(h8v*)&smh[H_TINB + fb + 384] = z;
            h8v j0, j1 = {};
            j0[0]=(_Float16)0.f;  j0[1]=(_Float16)0.f;  j0[2]=(_Float16)ix2;
            j0[3]=(_Float16)ix3;  j0[4]=(_Float16)ix4;  j0[5]=(_Float16)rel0;
            j0[6]=(_Float16)rel1; j0[7]=(_Float16)qx2;
            j1[0]=(_Float16)qx3;  j1[1]=(_Float16)qx4;  j1[2]=(_Float16)qv0;
            j1[3]=(_Float16)qv1;  j1[4]=(_Float16)iav;  j1[5]=(_Float16)qav;
            j1[6]=(_Float16)(ix7 - truncf(ix7));
            *(h8v*)&smh[H_JINB + fb]       = j0;
            *(h8v*)&smh[H_JINB + fb + 128] = j1;
            *(h8v*)&smh[H_JINB + fb + 256] = z;
            *(h8v*)&smh[H_JINB + fb + 384] = z;

            const float len = sqrtf(rel0*rel0 + rel1*rel1);
            const float inv = 1.f / (len + 1e-8f);
            smf[F_SCAL +       tq] = mask;
            smf[F_SCAL +  64 + tq] = len;
            smf[F_SCAL + 128 + tq] = -rel0 * inv;
            smf[F_SCAL + 192 + tq] = -rel1 * inv;
            smf[F_SCAL + 256 + tq] = ((ix8 == qx8) && (ix8 > 0.f)) ? 1.f : 0.f;
            smf[F_SCAL + 320 + tq] = ((truncf(ix7) == truncf(qx7)) && (ix7 > 0.f)) ? 1.f : 0.f;
        }
    }
    __syncthreads();

    // ---- P2: trunk L0 + joint MFMA/fold ------------------------------------
    float jf0[4] = {0,0,0,0}, jf1[4] = {0,0,0,0};
    layerK32_rw(afT0, tb0, smh + H_TINB, smh + H_ACTA, lane, w);
    {
        f4v bv[2], jwa[2], jwb[2];
        #pragma unroll
        for (int mi = 0; mi < 2; ++mi) {
            const int m0 = (2*w + mi)*16 + q*4;
            bv[mi]  = *(const f4v*)&jb0[m0];
            jwa[mi] = *(const f4v*)&jw1[m0*2];
            jwb[mi] = *(const f4v*)&jw1[m0*2 + 4];
        }
        #pragma unroll
        for (int nt = 0; nt < 4; ++nt) {
            h8v bf = *(const h8v*)&smh[H_JINB + (nt*64 + lane)*8];
            #pragma unroll
            for (int mi = 0; mi < 2; ++mi) {
                f4v a = bv[mi];
                a = __builtin_amdgcn_mfma_f32_16x16x32_f16(afJ0[mi], bf, a, 0, 0, 0);
                float jw[8] = {jwa[mi][0], jwa[mi][1], jwa[mi][2], jwa[mi][3],
                               jwb[mi][0], jwb[mi][1], jwb[mi][2], jwb[mi][3]};
                #pragma unroll
                for (int i = 0; i < 4; ++i) {
                    const float jh = fmaxf(a[i], 0.f);
                    jf0[nt] = fmaf(jh, jw[i*2+0], jf0[nt]);
                    jf1[nt] = fmaf(jh, jw[i*2+1], jf1[nt]);
                }
            }
        }
    }
    __syncthreads();

    // ---- P3: trunk L1 (ACTA -> ACTB, overwrites staged inputs) -------------
    layerK128_rw(afT1, tbs, smh + H_ACTA, smh + H_ACTB, lane, w);
    __syncthreads();

    // ---- P4: trunk L2 -> C regs; trunk/spring folds; reduce ----------------
    f4v accT[2][4];
    layerK128_regs_rw(afT2, tbs + 128, smh + H_ACTB, accT, lane, w);

    float f0[4] = {0,0,0,0}, f1[4] = {0,0,0,0}, f2[4] = {0,0,0,0};
    float sp[4] = {0,0,0,0};

    #pragma unroll
    for (int mi = 0; mi < 2; ++mi) {   // branch * trunk @ out_w
        const int m0 = (2*w + mi)*16 + q*4;
        f4v oa = *(const f4v*)&out_w[m0*3];
        f4v ob = *(const f4v*)&out_w[m0*3 + 4];
        f4v oc = *(const f4v*)&out_w[m0*3 + 8];
        float ow[12] = {oa[0],oa[1],oa[2],oa[3], ob[0],ob[1],ob[2],ob[3],
                        oc[0],oc[1],oc[2],oc[3]};
        #pragma unroll
        for (int nt = 0; nt < 4; ++nt)
            #pragma unroll
            for (int i = 0; i < 4; ++i) {
                const float prod = accT[mi][nt][i] * br[mi][i];
                f0[nt] = fmaf(prod, ow[i*3+0], f0[nt]);
                f1[nt] = fmaf(prod, ow[i*3+1], f1[nt]);
                f2[nt] = fmaf(prod, ow[i*3+2], f2[nt]);
            }
    }
    {   // spring partial over own-wave neurons
        float lenv[4];
        #pragma unroll
        for (int nt = 0; nt < 4; ++nt) lenv[nt] = smf[F_SCAL + 64 + nt*16 + r];
        #pragma unroll
        for (int mi = 0; mi < 2; ++mi) {
            const int m0 = (2*w + mi)*16 + q*4;
            f4v w0 = *(const f4v*)&sw0[m0];
            f4v b0 = *(const f4v*)&sb0[m0];
            f4v w1 = *(const f4v*)&sw1[m0];
            #pragma unroll
            for (int i = 0; i < 4; ++i)
                #pragma unroll
                for (int nt = 0; nt < 4; ++nt) {
                    const float sv = fmaxf(fmaf(lenv[nt], w0[i], b0[i]), 0.f);
                    sp[nt] = fmaf(sv, w1[i], sp[nt]);
                }
        }
    }
    #pragma unroll
    for (int nt = 0; nt < 4; ++nt) {
        float v[6] = {f0[nt], f1[nt], f2[nt], jf0[nt], jf1[nt], sp[nt]};
        #pragma unroll
        for (int k = 0; k < 6; ++k) {
            v[k] += __shfl_xor(v[k], 16);
            v[k] += __shfl_xor(v[k], 32);
        }
        if (lane < 16) {
            // stride 7 dwords: gcd(7,32)=1 -> conflict-free writes & reads
            float* rd = &fred[((nt*16 + r)*4 + w)*7];
            rd[0]=v[0]; rd[1]=v[1]; rd[2]=v[2]; rd[3]=v[3]; rd[4]=v[4]; rd[5]=v[5];
        }
    }
    __syncthreads();

    // ---- P5: final combine + store -----------------------------------------
    if (tid < 64) {
        const int t = tid;
        float s0=0.f, s1=0.f, s2=0.f, s3=0.f, s4=0.f, s5=0.f;
        #pragma unroll
        for (int ww = 0; ww < 4; ++ww) {
            const float* rd = &fred[(t*4 + ww)*7];
            s0 += rd[0]; s1 += rd[1]; s2 += rd[2];
            s3 += rd[3]; s4 += rd[4]; s5 += rd[5];
        }
        const float mask = smf[F_SCAL + t];
        const float dvx  = smf[F_SCAL + 128 + t];
        const float dvy  = smf[F_SCAL + 192 + t];
        const float hs   = smf[F_SCAL + 256 + t];
        const float hj   = smf[F_SCAL + 320 + t];
        const float sf = (s5 + sb1[0]) * hs;
        const float j0 = (s3 + jb1[0]) * hj;
        const float j1 = (s4 + jb1[1]) * hj;
        float* op = out + (((b*64 + o)*64) + t)*3;
        op[0] = (s0 + out_b[0])*mask + sf*dvx + j0;
        op[1] = (s1 + out_b[1])*mask + sf*dvy + j1;
        op[2] = (s2 + out_b[2])*mask;
    }
}

// ===========================================================================
extern "C" void kernel_launch(void* const* d_in, const int* in_sizes, int n_in,
                              void* d_out, int out_size, void* d_ws, size_t ws_size,
                              hipStream_t stream) {
    (void)in_sizes; (void)n_in; (void)out_size; (void)ws_size;
    _Float16* wsH = (_Float16*)d_ws;
    float* brw = (float*)d_ws + BR_OFF_F;

    prep_kernel<<<dim3(FRAG_BLOCKS + BR_BLOCKS), dim3(256), 0, stream>>>(
        (const float*)d_in[6],   // trunk_w0
        (const float*)d_in[8],   // trunk_ws
        (const float*)d_in[20],  // joint_w0
        (const float*)d_in[10],  // branch_w0
        (const float*)d_in[12],  // branch_ws
        (const float*)d_in[11],  // branch_b0
        (const float*)d_in[13],  // branch_bs
        (const float*)d_in[0],   // init_x
        wsH, brw);
    ff_kernel<<<dim3(64*64), dim3(256), 0, stream>>>(
        (const float*)d_in[0],  (const float*)d_in[1],  (const float*)d_in[2],
        (const float*)d_in[3],  (const float*)d_in[4],  (const float*)d_in[5],
        (const float*)d_in[7],  (const float*)d_in[9],                  // tb0, tbs
        (const float*)d_in[14], (const float*)d_in[15],                 // out_w, out_b
        (const float*)d_in[16], (const float*)d_in[17],                 // sw0, sb0
        (const float*)d_in[18], (const float*)d_in[19],                 // sw1, sb1
        (const float*)d_in[21],                                         // jb0
        (const float*)d_in[22], (const float*)d_in[23],                 // jw1, jb1
        wsH, brw, (float*)d_out);
}